// Round 2
// baseline (5823.882 us; speedup 1.0000x reference)
//
#include <hip/hip_runtime.h>
#include <math.h>

// ---------------------------------------------------------------------------
// GCNRecommender: 3x GCNConv (D=64) + linear head. N=300K nodes, E=1.2M edges.
// R6: both k_gemm and k_gather were LATENCY-SERIALIZED (k_gemm VGPR_Count=36:
// compiler emitted load->vmcnt(0)->FMA per k-group; VALUBusy 30% ==
// 5 waves * 256cyc / 600cyc latency; occupancy 38->63% changed nothing).
// Fix: explicit MLP in source. k_gemm: 2-deep register double-buffer over
// k-groups (4 next-kg X loads issued before current-kg FMAs, fully unrolled,
// parity-indexed -> static). k_gather: neighbor loop unrolled x4, 4
// independent loads in flight. All fp32.
// ---------------------------------------------------------------------------

// ---- CSR build -------------------------------------------------------------

__global__ void k_hist(const int* __restrict__ col, int* __restrict__ cnt, int e) {
    int i = blockIdx.x * blockDim.x + threadIdx.x;
    if (i < e) atomicAdd(&cnt[col[i]], 1);
}

// exclusive scan, 1024 elems/block (256 thr x 4)
__global__ void k_scan1(const int* __restrict__ cnt, int* __restrict__ offs,
                        int* __restrict__ bsum, int n) {
    __shared__ int s[256];
    const int t = threadIdx.x;
    const int base = blockIdx.x * 1024 + t * 4;
    int v[4], sum = 0;
    #pragma unroll
    for (int k = 0; k < 4; ++k) {
        v[k] = (base + k < n) ? cnt[base + k] : 0;
        sum += v[k];
    }
    s[t] = sum;
    __syncthreads();
    #pragma unroll
    for (int off = 1; off < 256; off <<= 1) {
        int x = (t >= off) ? s[t - off] : 0;
        __syncthreads();
        s[t] += x;
        __syncthreads();
    }
    int run = s[t] - sum;
    #pragma unroll
    for (int k = 0; k < 4; ++k) {
        if (base + k < n) offs[base + k] = run;
        run += v[k];
    }
    if (t == 255) bsum[blockIdx.x] = s[255];
}

__global__ void k_scan2(int* __restrict__ bsum, int nb) {
    __shared__ int s[512];
    const int t = threadIdx.x;
    int v = (t < nb) ? bsum[t] : 0;
    s[t] = v;
    __syncthreads();
    #pragma unroll
    for (int off = 1; off < 512; off <<= 1) {
        int x = (t >= off) ? s[t - off] : 0;
        __syncthreads();
        s[t] += x;
        __syncthreads();
    }
    if (t < nb) bsum[t] = s[t] - v;
}

__global__ void k_scan3(int* __restrict__ offs, const int* __restrict__ bsum,
                        int n, int e) {
    int i = blockIdx.x * blockDim.x + threadIdx.x;
    if (i < n) offs[i] += bsum[i >> 10];
    if (i == 0) offs[n] = e;
}

__global__ void k_fill(const int* __restrict__ row, const int* __restrict__ col,
                       const int* __restrict__ offs, int* __restrict__ cur,
                       int* __restrict__ elist, int e) {
    int i = blockIdx.x * blockDim.x + threadIdx.x;
    if (i < e) {
        int c = col[i];
        int pos = offs[c] + atomicAdd(&cur[c], 1);
        elist[pos] = row[i];
    }
}

__global__ void k_dinv(const int* __restrict__ cnt, float* __restrict__ dinv, int n) {
    int i = blockIdx.x * blockDim.x + threadIdx.x;
    if (i < n) dinv[i] = 1.0f / sqrtf((float)(cnt[i] + 1));  // +1 self-loop
}

// ---- GEMM: Y[r,:] = X[r,:] @ W ---------------------------------------------
// X source: (ut!=null) ? embedding tables (conv1) : dense X.
// Thread (cg=t&15, rbase=t>>4) computes rows rbase+16j, cols cg*4..cg*4+3.
// X read direct from global (16-lane broadcast per row); W in LDS (16 KB).
// Software pipeline: X loads for kg+1 issued before FMAs of kg (2-deep
// register double-buffer; loop fully unrolled so parity indices are static).
// Epilogue: dinv!=null -> Y = dinv[row]*y (conv; bias+relu in gather)
//           dinv==null -> Y = y + bias   (linear head)
__launch_bounds__(256, 4)
__global__ void k_gemm(const float* __restrict__ X,
                       const int* __restrict__ uid, const int* __restrict__ iid,
                       const float4* __restrict__ ut4, const float4* __restrict__ it4,
                       const float* __restrict__ W, const float* __restrict__ bias,
                       float* __restrict__ Y, const float* __restrict__ dinv,
                       int n, int u) {
    __shared__ __align__(16) float Ws[64 * 64];
    const int t  = threadIdx.x;
    const int rb = blockIdx.x * 64;

    const float4* W4 = (const float4*)W;
    float4* Ws4 = (float4*)Ws;
    #pragma unroll
    for (int idx = t; idx < 1024; idx += 256) Ws4[idx] = W4[idx];

    const int cg = t & 15;     // float4 col group
    const int rbase = t >> 4;  // rows rbase+16j

    // Per-j source pointers (row clamped for the ragged last block; store is
    // guarded so clamped rows produce no output).
    const float4* X4 = (const float4*)X;
    const float4* src[4];
    int rows[4];
    #pragma unroll
    for (int j = 0; j < 4; ++j) {
        int row_g = rb + rbase + 16 * j;
        rows[j] = row_g;
        int rc = min(row_g, n - 1);
        if (ut4 != nullptr) {
            src[j] = (rc < u) ? (ut4 + (size_t)uid[rc] * 16)
                              : (it4 + (size_t)iid[rc - u] * 16);
        } else {
            src[j] = X4 + (size_t)rc * 16;
        }
    }
    __syncthreads();

    float4 acc[4];
    #pragma unroll
    for (int j = 0; j < 4; ++j) acc[j] = make_float4(0.f, 0.f, 0.f, 0.f);

    // prologue: fill pipeline stage 0
    float4 xbuf[2][4];
    #pragma unroll
    for (int j = 0; j < 4; ++j) xbuf[0][j] = src[j][0];

    #pragma unroll
    for (int kg = 0; kg < 16; ++kg) {
        const int cur = kg & 1;
        const int nxt = cur ^ 1;
        // issue next k-group's 4 independent X loads BEFORE consuming current
        if (kg < 15) {
            #pragma unroll
            for (int j = 0; j < 4; ++j) xbuf[nxt][j] = src[j][kg + 1];
        }
        float4 w0 = Ws4[(4 * kg + 0) * 16 + cg];
        float4 w1 = Ws4[(4 * kg + 1) * 16 + cg];
        float4 w2 = Ws4[(4 * kg + 2) * 16 + cg];
        float4 w3 = Ws4[(4 * kg + 3) * 16 + cg];
        #pragma unroll
        for (int j = 0; j < 4; ++j) {
            float4 xr = xbuf[cur][j];
            acc[j].x = fmaf(xr.x, w0.x, acc[j].x); acc[j].y = fmaf(xr.x, w0.y, acc[j].y);
            acc[j].z = fmaf(xr.x, w0.z, acc[j].z); acc[j].w = fmaf(xr.x, w0.w, acc[j].w);
            acc[j].x = fmaf(xr.y, w1.x, acc[j].x); acc[j].y = fmaf(xr.y, w1.y, acc[j].y);
            acc[j].z = fmaf(xr.y, w1.z, acc[j].z); acc[j].w = fmaf(xr.y, w1.w, acc[j].w);
            acc[j].x = fmaf(xr.z, w2.x, acc[j].x); acc[j].y = fmaf(xr.z, w2.y, acc[j].y);
            acc[j].z = fmaf(xr.z, w2.z, acc[j].z); acc[j].w = fmaf(xr.z, w2.w, acc[j].w);
            acc[j].x = fmaf(xr.w, w3.x, acc[j].x); acc[j].y = fmaf(xr.w, w3.y, acc[j].y);
            acc[j].z = fmaf(xr.w, w3.z, acc[j].z); acc[j].w = fmaf(xr.w, w3.w, acc[j].w);
        }
    }

    const float4* b4 = (const float4*)bias;
    #pragma unroll
    for (int j = 0; j < 4; ++j) {
        int row = rows[j];
        if (row >= n) continue;
        float4 y = acc[j];
        if (dinv != nullptr) {
            float s = dinv[row];
            y.x *= s; y.y *= s; y.z *= s; y.w *= s;
        } else {
            float4 bb = b4[cg];
            y.x += bb.x; y.y += bb.y; y.z += bb.z; y.w += bb.w;
        }
        ((float4*)Y)[(size_t)row * 16 + cg] = y;
    }
}

// ---- gather: 16 lanes per node (4 nodes/wave, 16 nodes/block).
// OUT[c,:] = f( dinv[c] * (sum_{r in in(c)} Yn[r,:] + Yn[c,:]) + b ),
// f = relu (conv1/conv2 outputs) or identity (conv3 output).
// Neighbor loop unrolled x4: 4 independent row loads issued before any
// accumulate (eidx defaults to row 0 for q>=deg, so loads are always safe;
// the adds stay predicated).
__launch_bounds__(256)
__global__ void k_gather(const int* __restrict__ offs, const int* __restrict__ elist,
                         const float* __restrict__ dinv, const float4* __restrict__ Yn4,
                         const float4* __restrict__ b4, float4* __restrict__ OUT4,
                         int n, int relu_out) {
    const int t = threadIdx.x;
    const int nid = blockIdx.x * 16 + (t >> 4);  // this 16-lane group's node
    const int q = t & 15;                        // float4 column group
    const int gbase = t & 48;                    // first lane of this group
    if (nid >= n) return;

    const int beg = offs[nid];
    const int end = offs[nid + 1];
    const int deg = end - beg;

    // Issue independent loads early: self row, dinv, bias, first 16 edge idx.
    float4 self = Yn4[(size_t)nid * 16 + q];
    float dc = dinv[nid];
    float4 bb = b4[q];
    int eidx = (q < deg) ? elist[beg + q] : 0;   // safe default row 0

    // wave-wide max degree (groups diverge only in predicates, not trip count)
    int m = deg;
    m = max(m, __shfl_xor(m, 16, 64));
    m = max(m, __shfl_xor(m, 32, 64));
    m = min(m, 16);

    float4 acc = make_float4(0.f, 0.f, 0.f, 0.f);
    int j = 0;
    for (; j + 4 <= m; j += 4) {
        int r0 = __shfl(eidx, gbase + j + 0, 64);
        int r1 = __shfl(eidx, gbase + j + 1, 64);
        int r2 = __shfl(eidx, gbase + j + 2, 64);
        int r3 = __shfl(eidx, gbase + j + 3, 64);
        float4 v0 = Yn4[(size_t)r0 * 16 + q];    // 4 loads in flight
        float4 v1 = Yn4[(size_t)r1 * 16 + q];
        float4 v2 = Yn4[(size_t)r2 * 16 + q];
        float4 v3 = Yn4[(size_t)r3 * 16 + q];
        if (j + 0 < deg) { acc.x += v0.x; acc.y += v0.y; acc.z += v0.z; acc.w += v0.w; }
        if (j + 1 < deg) { acc.x += v1.x; acc.y += v1.y; acc.z += v1.z; acc.w += v1.w; }
        if (j + 2 < deg) { acc.x += v2.x; acc.y += v2.y; acc.z += v2.z; acc.w += v2.w; }
        if (j + 3 < deg) { acc.x += v3.x; acc.y += v3.y; acc.z += v3.z; acc.w += v3.w; }
    }
    for (; j < m; ++j) {
        int r = __shfl(eidx, gbase + j, 64);
        float4 v = Yn4[(size_t)r * 16 + q];
        if (j < deg) { acc.x += v.x; acc.y += v.y; acc.z += v.z; acc.w += v.w; }
    }
    // rare tail (deg > 16): ~0 nodes for Poisson(4), correctness only
    for (int jj = beg + 16; jj < end; ++jj) {
        int r = elist[jj];
        float4 v = Yn4[(size_t)r * 16 + q];
        acc.x += v.x; acc.y += v.y; acc.z += v.z; acc.w += v.w;
    }

    float4 o;
    o.x = fmaf(dc, acc.x + self.x, bb.x);
    o.y = fmaf(dc, acc.y + self.y, bb.y);
    o.z = fmaf(dc, acc.z + self.z, bb.z);
    o.w = fmaf(dc, acc.w + self.w, bb.w);
    if (relu_out) {
        o.x = fmaxf(o.x, 0.f); o.y = fmaxf(o.y, 0.f);
        o.z = fmaxf(o.z, 0.f); o.w = fmaxf(o.w, 0.f);
    }
    OUT4[(size_t)nid * 16 + q] = o;
}

// ---------------------------------------------------------------------------

extern "C" void kernel_launch(void* const* d_in, const int* in_sizes, int n_in,
                              void* d_out, int out_size, void* d_ws, size_t ws_size,
                              hipStream_t stream) {
    const int*   user_ids = (const int*)d_in[0];
    const int*   item_ids = (const int*)d_in[1];
    const int*   edge     = (const int*)d_in[2];
    const float* ut   = (const float*)d_in[4];
    const float* it   = (const float*)d_in[5];
    const float* W1   = (const float*)d_in[6];
    const float* b1   = (const float*)d_in[7];
    const float* W2   = (const float*)d_in[8];
    const float* b2   = (const float*)d_in[9];
    const float* W3   = (const float*)d_in[10];
    const float* b3   = (const float*)d_in[11];
    const float* linW = (const float*)d_in[12];
    const float* linb = (const float*)d_in[13];

    const int u = in_sizes[0];
    const int iN = in_sizes[1];
    const int e = in_sizes[2] / 2;
    const int n = u + iN;

    // workspace layout
    float* A    = (float*)d_ws;                       // [n,64] node features
    float* dinv = A + (size_t)n * 64;                 // [n]
    int*   cnt  = (int*)(dinv + n);                   // [n]  (reused as cursor)
    int*   offs = cnt + n;                            // [n+1]
    int*   bsum = offs + n + 1;                       // [nb]
    int*   elist = bsum + 1024;                       // [e]
    float* Yn   = (float*)d_out;                      // [n,64] scratch; final out

    const int* erow = edge;
    const int* ecol = edge + e;

    const int B = 256;
    const int nb = (n + 1023) / 1024;

    // ---- CSR build + dinv ----
    hipMemsetAsync(cnt, 0, (size_t)n * sizeof(int), stream);
    k_hist<<<(e + B - 1) / B, B, 0, stream>>>(ecol, cnt, e);
    k_scan1<<<nb, 256, 0, stream>>>(cnt, offs, bsum, n);
    k_scan2<<<1, 512, 0, stream>>>(bsum, nb);
    k_scan3<<<(n + B - 1) / B, B, 0, stream>>>(offs, bsum, n, e);
    k_dinv<<<(n + B - 1) / B, B, 0, stream>>>(cnt, dinv, n);
    hipMemsetAsync(cnt, 0, (size_t)n * sizeof(int), stream);  // cursor
    k_fill<<<(e + B - 1) / B, B, 0, stream>>>(erow, ecol, offs, cnt, elist, e);

    const int gemm_grid = (n + 63) / 64;
    const int gath_grid = (n + 15) / 16;  // 16 nodes/block (16 lanes/node)

    // conv1 (embed fused into GEMM address calc)
    k_gemm<<<gemm_grid, B, 0, stream>>>(nullptr, user_ids, item_ids,
                                        (const float4*)ut, (const float4*)it,
                                        W1, nullptr, Yn, dinv, n, u);
    k_gather<<<gath_grid, B, 0, stream>>>(offs, elist, dinv, (const float4*)Yn,
                                          (const float4*)b1, (float4*)A, n, 1);
    // conv2 (relu already applied at gather1 store)
    k_gemm<<<gemm_grid, B, 0, stream>>>(A, nullptr, nullptr, nullptr, nullptr,
                                        W2, nullptr, Yn, dinv, n, u);
    k_gather<<<gath_grid, B, 0, stream>>>(offs, elist, dinv, (const float4*)Yn,
                                          (const float4*)b2, (float4*)A, n, 1);
    // conv3
    k_gemm<<<gemm_grid, B, 0, stream>>>(A, nullptr, nullptr, nullptr, nullptr,
                                        W3, nullptr, Yn, dinv, n, u);
    k_gather<<<gath_grid, B, 0, stream>>>(offs, elist, dinv, (const float4*)Yn,
                                          (const float4*)b3, (float4*)A, n, 0);
    // mean-pool = identity; linear head -> d_out
    k_gemm<<<gemm_grid, B, 0, stream>>>(A, nullptr, nullptr, nullptr, nullptr,
                                        linW, linb, (float*)d_out, nullptr, n, u);
}

// Round 3
// 5485.951 us; speedup vs baseline: 1.0616x; 1.0616x over previous
//
#include <hip/hip_runtime.h>
#include <math.h>

// ---------------------------------------------------------------------------
// GCNRecommender: 3x GCNConv (D=64) + linear head. N=300K nodes, E=1.2M edges.
// R7: R6's xbuf[2][4] pipeline spilled to scratch (compiler didn't fully
// unroll the kg loop -> cur=kg&1 runtime -> local memory; FETCH 2.46GB,
// WRITE 1.73GB, 1383us). Same 2-deep MLP pipeline re-expressed with ONLY
// named variables (xa0..3 / xb0..3 / acc0..3 / src0..3), kg-step-2 loop:
// no runtime-indexed array exists, so nothing can spill regardless of
// unrolling. Gather keeps x4-unrolled independent loads. All fp32.
// ---------------------------------------------------------------------------

// ---- CSR build -------------------------------------------------------------

__global__ void k_hist(const int* __restrict__ col, int* __restrict__ cnt, int e) {
    int i = blockIdx.x * blockDim.x + threadIdx.x;
    if (i < e) atomicAdd(&cnt[col[i]], 1);
}

// exclusive scan, 1024 elems/block (256 thr x 4)
__global__ void k_scan1(const int* __restrict__ cnt, int* __restrict__ offs,
                        int* __restrict__ bsum, int n) {
    __shared__ int s[256];
    const int t = threadIdx.x;
    const int base = blockIdx.x * 1024 + t * 4;
    int v[4], sum = 0;
    #pragma unroll
    for (int k = 0; k < 4; ++k) {
        v[k] = (base + k < n) ? cnt[base + k] : 0;
        sum += v[k];
    }
    s[t] = sum;
    __syncthreads();
    #pragma unroll
    for (int off = 1; off < 256; off <<= 1) {
        int x = (t >= off) ? s[t - off] : 0;
        __syncthreads();
        s[t] += x;
        __syncthreads();
    }
    int run = s[t] - sum;
    #pragma unroll
    for (int k = 0; k < 4; ++k) {
        if (base + k < n) offs[base + k] = run;
        run += v[k];
    }
    if (t == 255) bsum[blockIdx.x] = s[255];
}

__global__ void k_scan2(int* __restrict__ bsum, int nb) {
    __shared__ int s[512];
    const int t = threadIdx.x;
    int v = (t < nb) ? bsum[t] : 0;
    s[t] = v;
    __syncthreads();
    #pragma unroll
    for (int off = 1; off < 512; off <<= 1) {
        int x = (t >= off) ? s[t - off] : 0;
        __syncthreads();
        s[t] += x;
        __syncthreads();
    }
    if (t < nb) bsum[t] = s[t] - v;
}

__global__ void k_scan3(int* __restrict__ offs, const int* __restrict__ bsum,
                        int n, int e) {
    int i = blockIdx.x * blockDim.x + threadIdx.x;
    if (i < n) offs[i] += bsum[i >> 10];
    if (i == 0) offs[n] = e;
}

__global__ void k_fill(const int* __restrict__ row, const int* __restrict__ col,
                       const int* __restrict__ offs, int* __restrict__ cur,
                       int* __restrict__ elist, int e) {
    int i = blockIdx.x * blockDim.x + threadIdx.x;
    if (i < e) {
        int c = col[i];
        int pos = offs[c] + atomicAdd(&cur[c], 1);
        elist[pos] = row[i];
    }
}

__global__ void k_dinv(const int* __restrict__ cnt, float* __restrict__ dinv, int n) {
    int i = blockIdx.x * blockDim.x + threadIdx.x;
    if (i < n) dinv[i] = 1.0f / sqrtf((float)(cnt[i] + 1));  // +1 self-loop
}

// ---- GEMM: Y[r,:] = X[r,:] @ W ---------------------------------------------
// X source: (ut!=null) ? embedding tables (conv1) : dense X.
// Thread (cg=t&15, rbase=t>>4) computes rows rbase+16j, cols cg*4..cg*4+3.
// X read direct from global (16-lane broadcast per row); W in LDS (16 KB).
// 2-deep software pipeline over k-groups with NAMED register buffers only
// (xa*/xb*), kg-step-2 loop: scratch-proof by construction (rule #20).
// Epilogue: dinv!=null -> Y = dinv[row]*y (conv; bias+relu in gather)
//           dinv==null -> Y = y + bias   (linear head)

#define FMA4(xr, a)                                                          \
    a.x = fmaf(xr.x, w0.x, a.x); a.y = fmaf(xr.x, w0.y, a.y);                \
    a.z = fmaf(xr.x, w0.z, a.z); a.w = fmaf(xr.x, w0.w, a.w);                \
    a.x = fmaf(xr.y, w1.x, a.x); a.y = fmaf(xr.y, w1.y, a.y);                \
    a.z = fmaf(xr.y, w1.z, a.z); a.w = fmaf(xr.y, w1.w, a.w);                \
    a.x = fmaf(xr.z, w2.x, a.x); a.y = fmaf(xr.z, w2.y, a.y);                \
    a.z = fmaf(xr.z, w2.z, a.z); a.w = fmaf(xr.z, w2.w, a.w);                \
    a.x = fmaf(xr.w, w3.x, a.x); a.y = fmaf(xr.w, w3.y, a.y);                \
    a.z = fmaf(xr.w, w3.z, a.z); a.w = fmaf(xr.w, w3.w, a.w);

#define KG_BODY(X0, X1, X2, X3, KG)                                          \
    {                                                                        \
        float4 w0 = Ws4[(4 * (KG) + 0) * 16 + cg];                           \
        float4 w1 = Ws4[(4 * (KG) + 1) * 16 + cg];                           \
        float4 w2 = Ws4[(4 * (KG) + 2) * 16 + cg];                           \
        float4 w3 = Ws4[(4 * (KG) + 3) * 16 + cg];                           \
        FMA4(X0, acc0) FMA4(X1, acc1) FMA4(X2, acc2) FMA4(X3, acc3)          \
    }

__launch_bounds__(256, 4)
__global__ void k_gemm(const float* __restrict__ X,
                       const int* __restrict__ uid, const int* __restrict__ iid,
                       const float4* __restrict__ ut4, const float4* __restrict__ it4,
                       const float* __restrict__ W, const float* __restrict__ bias,
                       float* __restrict__ Y, const float* __restrict__ dinv,
                       int n, int u) {
    __shared__ __align__(16) float Ws[64 * 64];
    const int t  = threadIdx.x;
    const int rb = blockIdx.x * 64;

    const float4* W4 = (const float4*)W;
    float4* Ws4 = (float4*)Ws;
    #pragma unroll
    for (int idx = t; idx < 1024; idx += 256) Ws4[idx] = W4[idx];

    const int cg = t & 15;     // float4 col group
    const int rbase = t >> 4;  // rows rbase+16j

    // Per-j source pointers (row clamped for the ragged last block; store is
    // guarded so clamped rows produce no output). Named, not arrays.
    const float4* X4 = (const float4*)X;
    const float4 *src0, *src1, *src2, *src3;
    int rows0, rows1, rows2, rows3;
#define SETSRC(SRC, ROWS, J)                                                 \
    {                                                                        \
        int row_g = rb + rbase + 16 * (J);                                   \
        ROWS = row_g;                                                        \
        int rc = min(row_g, n - 1);                                          \
        if (ut4 != nullptr) {                                                \
            SRC = (rc < u) ? (ut4 + (size_t)uid[rc] * 16)                    \
                           : (it4 + (size_t)iid[rc - u] * 16);               \
        } else {                                                             \
            SRC = X4 + (size_t)rc * 16;                                      \
        }                                                                    \
    }
    SETSRC(src0, rows0, 0)
    SETSRC(src1, rows1, 1)
    SETSRC(src2, rows2, 2)
    SETSRC(src3, rows3, 3)
#undef SETSRC
    __syncthreads();

    float4 acc0 = make_float4(0.f, 0.f, 0.f, 0.f);
    float4 acc1 = make_float4(0.f, 0.f, 0.f, 0.f);
    float4 acc2 = make_float4(0.f, 0.f, 0.f, 0.f);
    float4 acc3 = make_float4(0.f, 0.f, 0.f, 0.f);

    // prologue: stage A holds kg=0
    float4 xa0 = src0[0], xa1 = src1[0], xa2 = src2[0], xa3 = src3[0];
    float4 xb0, xb1, xb2, xb3;

    #pragma unroll
    for (int kg = 0; kg < 16; kg += 2) {
        // prefetch kg+1 into B before consuming A
        xb0 = src0[kg + 1]; xb1 = src1[kg + 1];
        xb2 = src2[kg + 1]; xb3 = src3[kg + 1];
        KG_BODY(xa0, xa1, xa2, xa3, kg)
        // prefetch kg+2 into A before consuming B
        if (kg + 2 < 16) {
            xa0 = src0[kg + 2]; xa1 = src1[kg + 2];
            xa2 = src2[kg + 2]; xa3 = src3[kg + 2];
        }
        KG_BODY(xb0, xb1, xb2, xb3, kg + 1)
    }

    const float4* b4 = (const float4*)bias;
#define EPI(ACC, ROW)                                                        \
    if ((ROW) < n) {                                                         \
        float4 y = ACC;                                                      \
        if (dinv != nullptr) {                                               \
            float s = dinv[ROW];                                             \
            y.x *= s; y.y *= s; y.z *= s; y.w *= s;                          \
        } else {                                                             \
            float4 bb = b4[cg];                                              \
            y.x += bb.x; y.y += bb.y; y.z += bb.z; y.w += bb.w;              \
        }                                                                    \
        ((float4*)Y)[(size_t)(ROW) * 16 + cg] = y;                           \
    }
    EPI(acc0, rows0)
    EPI(acc1, rows1)
    EPI(acc2, rows2)
    EPI(acc3, rows3)
#undef EPI
}

// ---- gather: 16 lanes per node (4 nodes/wave, 16 nodes/block).
// OUT[c,:] = f( dinv[c] * (sum_{r in in(c)} Yn[r,:] + Yn[c,:]) + b ),
// f = relu (conv1/conv2 outputs) or identity (conv3 output).
// Neighbor loop unrolled x4: 4 independent row loads issued before any
// accumulate (eidx defaults to row 0 for q>=deg, so loads are always safe;
// the adds stay predicated). Named scalars only -- scratch-proof.
__launch_bounds__(256)
__global__ void k_gather(const int* __restrict__ offs, const int* __restrict__ elist,
                         const float* __restrict__ dinv, const float4* __restrict__ Yn4,
                         const float4* __restrict__ b4, float4* __restrict__ OUT4,
                         int n, int relu_out) {
    const int t = threadIdx.x;
    const int nid = blockIdx.x * 16 + (t >> 4);  // this 16-lane group's node
    const int q = t & 15;                        // float4 column group
    const int gbase = t & 48;                    // first lane of this group
    if (nid >= n) return;

    const int beg = offs[nid];
    const int end = offs[nid + 1];
    const int deg = end - beg;

    // Issue independent loads early: self row, dinv, bias, first 16 edge idx.
    float4 self = Yn4[(size_t)nid * 16 + q];
    float dc = dinv[nid];
    float4 bb = b4[q];
    int eidx = (q < deg) ? elist[beg + q] : 0;   // safe default row 0

    // wave-wide max degree (groups diverge only in predicates, not trip count)
    int m = deg;
    m = max(m, __shfl_xor(m, 16, 64));
    m = max(m, __shfl_xor(m, 32, 64));
    m = min(m, 16);

    float4 acc = make_float4(0.f, 0.f, 0.f, 0.f);
    int j = 0;
    for (; j + 4 <= m; j += 4) {
        int r0 = __shfl(eidx, gbase + j + 0, 64);
        int r1 = __shfl(eidx, gbase + j + 1, 64);
        int r2 = __shfl(eidx, gbase + j + 2, 64);
        int r3 = __shfl(eidx, gbase + j + 3, 64);
        float4 v0 = Yn4[(size_t)r0 * 16 + q];    // 4 loads in flight
        float4 v1 = Yn4[(size_t)r1 * 16 + q];
        float4 v2 = Yn4[(size_t)r2 * 16 + q];
        float4 v3 = Yn4[(size_t)r3 * 16 + q];
        if (j + 0 < deg) { acc.x += v0.x; acc.y += v0.y; acc.z += v0.z; acc.w += v0.w; }
        if (j + 1 < deg) { acc.x += v1.x; acc.y += v1.y; acc.z += v1.z; acc.w += v1.w; }
        if (j + 2 < deg) { acc.x += v2.x; acc.y += v2.y; acc.z += v2.z; acc.w += v2.w; }
        if (j + 3 < deg) { acc.x += v3.x; acc.y += v3.y; acc.z += v3.z; acc.w += v3.w; }
    }
    for (; j < m; ++j) {
        int r = __shfl(eidx, gbase + j, 64);
        float4 v = Yn4[(size_t)r * 16 + q];
        if (j < deg) { acc.x += v.x; acc.y += v.y; acc.z += v.z; acc.w += v.w; }
    }
    // rare tail (deg > 16): ~0 nodes for Poisson(4), correctness only
    for (int jj = beg + 16; jj < end; ++jj) {
        int r = elist[jj];
        float4 v = Yn4[(size_t)r * 16 + q];
        acc.x += v.x; acc.y += v.y; acc.z += v.z; acc.w += v.w;
    }

    float4 o;
    o.x = fmaf(dc, acc.x + self.x, bb.x);
    o.y = fmaf(dc, acc.y + self.y, bb.y);
    o.z = fmaf(dc, acc.z + self.z, bb.z);
    o.w = fmaf(dc, acc.w + self.w, bb.w);
    if (relu_out) {
        o.x = fmaxf(o.x, 0.f); o.y = fmaxf(o.y, 0.f);
        o.z = fmaxf(o.z, 0.f); o.w = fmaxf(o.w, 0.f);
    }
    OUT4[(size_t)nid * 16 + q] = o;
}

// ---------------------------------------------------------------------------

extern "C" void kernel_launch(void* const* d_in, const int* in_sizes, int n_in,
                              void* d_out, int out_size, void* d_ws, size_t ws_size,
                              hipStream_t stream) {
    const int*   user_ids = (const int*)d_in[0];
    const int*   item_ids = (const int*)d_in[1];
    const int*   edge     = (const int*)d_in[2];
    const float* ut   = (const float*)d_in[4];
    const float* it   = (const float*)d_in[5];
    const float* W1   = (const float*)d_in[6];
    const float* b1   = (const float*)d_in[7];
    const float* W2   = (const float*)d_in[8];
    const float* b2   = (const float*)d_in[9];
    const float* W3   = (const float*)d_in[10];
    const float* b3   = (const float*)d_in[11];
    const float* linW = (const float*)d_in[12];
    const float* linb = (const float*)d_in[13];

    const int u = in_sizes[0];
    const int iN = in_sizes[1];
    const int e = in_sizes[2] / 2;
    const int n = u + iN;

    // workspace layout
    float* A    = (float*)d_ws;                       // [n,64] node features
    float* dinv = A + (size_t)n * 64;                 // [n]
    int*   cnt  = (int*)(dinv + n);                   // [n]  (reused as cursor)
    int*   offs = cnt + n;                            // [n+1]
    int*   bsum = offs + n + 1;                       // [nb]
    int*   elist = bsum + 1024;                       // [e]
    float* Yn   = (float*)d_out;                      // [n,64] scratch; final out

    const int* erow = edge;
    const int* ecol = edge + e;

    const int B = 256;
    const int nb = (n + 1023) / 1024;

    // ---- CSR build + dinv ----
    hipMemsetAsync(cnt, 0, (size_t)n * sizeof(int), stream);
    k_hist<<<(e + B - 1) / B, B, 0, stream>>>(ecol, cnt, e);
    k_scan1<<<nb, 256, 0, stream>>>(cnt, offs, bsum, n);
    k_scan2<<<1, 512, 0, stream>>>(bsum, nb);
    k_scan3<<<(n + B - 1) / B, B, 0, stream>>>(offs, bsum, n, e);
    k_dinv<<<(n + B - 1) / B, B, 0, stream>>>(cnt, dinv, n);
    hipMemsetAsync(cnt, 0, (size_t)n * sizeof(int), stream);  // cursor
    k_fill<<<(e + B - 1) / B, B, 0, stream>>>(erow, ecol, offs, cnt, elist, e);

    const int gemm_grid = (n + 63) / 64;
    const int gath_grid = (n + 15) / 16;  // 16 nodes/block (16 lanes/node)

    // conv1 (embed fused into GEMM address calc)
    k_gemm<<<gemm_grid, B, 0, stream>>>(nullptr, user_ids, item_ids,
                                        (const float4*)ut, (const float4*)it,
                                        W1, nullptr, Yn, dinv, n, u);
    k_gather<<<gath_grid, B, 0, stream>>>(offs, elist, dinv, (const float4*)Yn,
                                          (const float4*)b1, (float4*)A, n, 1);
    // conv2 (relu applied at gather1 store)
    k_gemm<<<gemm_grid, B, 0, stream>>>(A, nullptr, nullptr, nullptr, nullptr,
                                        W2, nullptr, Yn, dinv, n, u);
    k_gather<<<gath_grid, B, 0, stream>>>(offs, elist, dinv, (const float4*)Yn,
                                          (const float4*)b2, (float4*)A, n, 1);
    // conv3
    k_gemm<<<gemm_grid, B, 0, stream>>>(A, nullptr, nullptr, nullptr, nullptr,
                                        W3, nullptr, Yn, dinv, n, u);
    k_gather<<<gath_grid, B, 0, stream>>>(offs, elist, dinv, (const float4*)Yn,
                                          (const float4*)b3, (float4*)A, n, 0);
    // mean-pool = identity; linear head -> d_out
    k_gemm<<<gemm_grid, B, 0, stream>>>(A, nullptr, nullptr, nullptr, nullptr,
                                        linW, linb, (float*)d_out, nullptr, n, u);
}

// Round 4
// 3185.489 us; speedup vs baseline: 1.8283x; 1.7222x over previous
//
#include <hip/hip_runtime.h>
#include <math.h>

// ---------------------------------------------------------------------------
// GCNRecommender: 3x GCNConv (D=64) + linear head. N=300K nodes, E=1.2M edges.
// R8: R6/R7 loop-carried register prefetch both spilled (compiler hoists
// in-flight loads across iterations -> allocator overrun -> scratch; 2.2GB
// FETCH, 1.3ms). Replacement: PHASED BURST. 4 phases over K; each phase does
// 16 independent named float4 loads (64B contiguous per row), then the FMA
// block; __builtin_amdgcn_sched_barrier(0) between phases forbids cross-phase
// hoisting entirely -> bounded pressure, no loop-carried state, no spill
// possible. Latency exposed 4x/wave (was 16x in R5) with 16-deep MLP each.
// launch_bounds(256,2) gives the allocator headroom (~120 VGPR expected).
// ---------------------------------------------------------------------------

// ---- CSR build -------------------------------------------------------------

__global__ void k_hist(const int* __restrict__ col, int* __restrict__ cnt, int e) {
    int i = blockIdx.x * blockDim.x + threadIdx.x;
    if (i < e) atomicAdd(&cnt[col[i]], 1);
}

// exclusive scan, 1024 elems/block (256 thr x 4)
__global__ void k_scan1(const int* __restrict__ cnt, int* __restrict__ offs,
                        int* __restrict__ bsum, int n) {
    __shared__ int s[256];
    const int t = threadIdx.x;
    const int base = blockIdx.x * 1024 + t * 4;
    int v[4], sum = 0;
    #pragma unroll
    for (int k = 0; k < 4; ++k) {
        v[k] = (base + k < n) ? cnt[base + k] : 0;
        sum += v[k];
    }
    s[t] = sum;
    __syncthreads();
    #pragma unroll
    for (int off = 1; off < 256; off <<= 1) {
        int x = (t >= off) ? s[t - off] : 0;
        __syncthreads();
        s[t] += x;
        __syncthreads();
    }
    int run = s[t] - sum;
    #pragma unroll
    for (int k = 0; k < 4; ++k) {
        if (base + k < n) offs[base + k] = run;
        run += v[k];
    }
    if (t == 255) bsum[blockIdx.x] = s[255];
}

__global__ void k_scan2(int* __restrict__ bsum, int nb) {
    __shared__ int s[512];
    const int t = threadIdx.x;
    int v = (t < nb) ? bsum[t] : 0;
    s[t] = v;
    __syncthreads();
    #pragma unroll
    for (int off = 1; off < 512; off <<= 1) {
        int x = (t >= off) ? s[t - off] : 0;
        __syncthreads();
        s[t] += x;
        __syncthreads();
    }
    if (t < nb) bsum[t] = s[t] - v;
}

__global__ void k_scan3(int* __restrict__ offs, const int* __restrict__ bsum,
                        int n, int e) {
    int i = blockIdx.x * blockDim.x + threadIdx.x;
    if (i < n) offs[i] += bsum[i >> 10];
    if (i == 0) offs[n] = e;
}

__global__ void k_fill(const int* __restrict__ row, const int* __restrict__ col,
                       const int* __restrict__ offs, int* __restrict__ cur,
                       int* __restrict__ elist, int e) {
    int i = blockIdx.x * blockDim.x + threadIdx.x;
    if (i < e) {
        int c = col[i];
        int pos = offs[c] + atomicAdd(&cur[c], 1);
        elist[pos] = row[i];
    }
}

__global__ void k_dinv(const int* __restrict__ cnt, float* __restrict__ dinv, int n) {
    int i = blockIdx.x * blockDim.x + threadIdx.x;
    if (i < n) dinv[i] = 1.0f / sqrtf((float)(cnt[i] + 1));  // +1 self-loop
}

// ---- GEMM: Y[r,:] = X[r,:] @ W ---------------------------------------------
// X source: (ut!=null) ? embedding tables (conv1) : dense X.
// Thread (cg=t&15, rbase=t>>4) computes rows rbase+16j, cols cg*4..cg*4+3.
// X read direct from global (16-lane broadcast per row); W in LDS (16 KB).
// 4-phase burst: each phase loads 16 named float4 (4 rows x 4 kg, 64B
// contiguous per row), then runs the FMA block; sched_barrier(0) between
// phases prevents cross-phase load hoisting (the R6/R7 spill mechanism).
// Epilogue: dinv!=null -> Y = dinv[row]*y (conv; bias+relu in gather)
//           dinv==null -> Y = y + bias   (linear head)

#define FMA4(xr, a)                                                          \
    a.x = fmaf(xr.x, w0.x, a.x); a.y = fmaf(xr.x, w0.y, a.y);                \
    a.z = fmaf(xr.x, w0.z, a.z); a.w = fmaf(xr.x, w0.w, a.w);                \
    a.x = fmaf(xr.y, w1.x, a.x); a.y = fmaf(xr.y, w1.y, a.y);                \
    a.z = fmaf(xr.y, w1.z, a.z); a.w = fmaf(xr.y, w1.w, a.w);                \
    a.x = fmaf(xr.z, w2.x, a.x); a.y = fmaf(xr.z, w2.y, a.y);                \
    a.z = fmaf(xr.z, w2.z, a.z); a.w = fmaf(xr.z, w2.w, a.w);                \
    a.x = fmaf(xr.w, w3.x, a.x); a.y = fmaf(xr.w, w3.y, a.y);                \
    a.z = fmaf(xr.w, w3.z, a.z); a.w = fmaf(xr.w, w3.w, a.w);

// 16 independent loads: row j, k-chunks 4P..4P+3 (64B contiguous per row)
#define LOADP(P)                                                             \
    xA0 = src0[4*(P)+0]; xA1 = src0[4*(P)+1];                                \
    xA2 = src0[4*(P)+2]; xA3 = src0[4*(P)+3];                                \
    xB0 = src1[4*(P)+0]; xB1 = src1[4*(P)+1];                                \
    xB2 = src1[4*(P)+2]; xB3 = src1[4*(P)+3];                                \
    xC0 = src2[4*(P)+0]; xC1 = src2[4*(P)+1];                                \
    xC2 = src2[4*(P)+2]; xC3 = src2[4*(P)+3];                                \
    xD0 = src3[4*(P)+0]; xD1 = src3[4*(P)+1];                                \
    xD2 = src3[4*(P)+2]; xD3 = src3[4*(P)+3];

#define KG1(KG, XA, XB, XC, XD)                                              \
    {                                                                        \
        float4 w0 = Ws4[(4 * (KG) + 0) * 16 + cg];                           \
        float4 w1 = Ws4[(4 * (KG) + 1) * 16 + cg];                           \
        float4 w2 = Ws4[(4 * (KG) + 2) * 16 + cg];                           \
        float4 w3 = Ws4[(4 * (KG) + 3) * 16 + cg];                           \
        FMA4(XA, acc0) FMA4(XB, acc1) FMA4(XC, acc2) FMA4(XD, acc3)          \
    }

#define COMPP(P)                                                             \
    KG1(4*(P)+0, xA0, xB0, xC0, xD0)                                         \
    KG1(4*(P)+1, xA1, xB1, xC1, xD1)                                         \
    KG1(4*(P)+2, xA2, xB2, xC2, xD2)                                         \
    KG1(4*(P)+3, xA3, xB3, xC3, xD3)

__launch_bounds__(256, 2)
__global__ void k_gemm(const float* __restrict__ X,
                       const int* __restrict__ uid, const int* __restrict__ iid,
                       const float4* __restrict__ ut4, const float4* __restrict__ it4,
                       const float* __restrict__ W, const float* __restrict__ bias,
                       float* __restrict__ Y, const float* __restrict__ dinv,
                       int n, int u) {
    __shared__ __align__(16) float Ws[64 * 64];
    const int t  = threadIdx.x;
    const int rb = blockIdx.x * 64;

    const float4* W4 = (const float4*)W;
    float4* Ws4 = (float4*)Ws;
    #pragma unroll
    for (int idx = t; idx < 1024; idx += 256) Ws4[idx] = W4[idx];

    const int cg = t & 15;     // float4 col group
    const int rbase = t >> 4;  // rows rbase+16j

    // Per-j source pointers (row clamped for the ragged last block; store is
    // guarded so clamped rows produce no output).
    const float4* X4 = (const float4*)X;
    const float4 *src0, *src1, *src2, *src3;
    int rows0, rows1, rows2, rows3;
#define SETSRC(SRC, ROWS, J)                                                 \
    {                                                                        \
        int row_g = rb + rbase + 16 * (J);                                   \
        ROWS = row_g;                                                        \
        int rc = min(row_g, n - 1);                                          \
        if (ut4 != nullptr) {                                                \
            SRC = (rc < u) ? (ut4 + (size_t)uid[rc] * 16)                    \
                           : (it4 + (size_t)iid[rc - u] * 16);               \
        } else {                                                             \
            SRC = X4 + (size_t)rc * 16;                                      \
        }                                                                    \
    }
    SETSRC(src0, rows0, 0)
    SETSRC(src1, rows1, 1)
    SETSRC(src2, rows2, 2)
    SETSRC(src3, rows3, 3)
#undef SETSRC
    __syncthreads();

    float4 acc0 = make_float4(0.f, 0.f, 0.f, 0.f);
    float4 acc1 = make_float4(0.f, 0.f, 0.f, 0.f);
    float4 acc2 = make_float4(0.f, 0.f, 0.f, 0.f);
    float4 acc3 = make_float4(0.f, 0.f, 0.f, 0.f);

    float4 xA0, xA1, xA2, xA3;
    float4 xB0, xB1, xB2, xB3;
    float4 xC0, xC1, xC2, xC3;
    float4 xD0, xD1, xD2, xD3;

    LOADP(0)
    COMPP(0)
    __builtin_amdgcn_sched_barrier(0);
    LOADP(1)
    COMPP(1)
    __builtin_amdgcn_sched_barrier(0);
    LOADP(2)
    COMPP(2)
    __builtin_amdgcn_sched_barrier(0);
    LOADP(3)
    COMPP(3)

    const float4* b4 = (const float4*)bias;
#define EPI(ACC, ROW)                                                        \
    if ((ROW) < n) {                                                         \
        float4 y = ACC;                                                      \
        if (dinv != nullptr) {                                               \
            float s = dinv[ROW];                                             \
            y.x *= s; y.y *= s; y.z *= s; y.w *= s;                          \
        } else {                                                             \
            float4 bb = b4[cg];                                              \
            y.x += bb.x; y.y += bb.y; y.z += bb.z; y.w += bb.w;              \
        }                                                                    \
        ((float4*)Y)[(size_t)(ROW) * 16 + cg] = y;                           \
    }
    EPI(acc0, rows0)
    EPI(acc1, rows1)
    EPI(acc2, rows2)
    EPI(acc3, rows3)
#undef EPI
}

// ---- gather: 16 lanes per node (4 nodes/wave, 16 nodes/block).
// OUT[c,:] = f( dinv[c] * (sum_{r in in(c)} Yn[r,:] + Yn[c,:]) + b ),
// f = relu (conv1/conv2 outputs) or identity (conv3 output).
// Neighbor loop unrolled x4: 4 independent row loads issued before any
// accumulate (eidx defaults to row 0 for q>=deg, so loads are always safe;
// the adds stay predicated). Named scalars only -- scratch-proof.
__launch_bounds__(256)
__global__ void k_gather(const int* __restrict__ offs, const int* __restrict__ elist,
                         const float* __restrict__ dinv, const float4* __restrict__ Yn4,
                         const float4* __restrict__ b4, float4* __restrict__ OUT4,
                         int n, int relu_out) {
    const int t = threadIdx.x;
    const int nid = blockIdx.x * 16 + (t >> 4);  // this 16-lane group's node
    const int q = t & 15;                        // float4 column group
    const int gbase = t & 48;                    // first lane of this group
    if (nid >= n) return;

    const int beg = offs[nid];
    const int end = offs[nid + 1];
    const int deg = end - beg;

    // Issue independent loads early: self row, dinv, bias, first 16 edge idx.
    float4 self = Yn4[(size_t)nid * 16 + q];
    float dc = dinv[nid];
    float4 bb = b4[q];
    int eidx = (q < deg) ? elist[beg + q] : 0;   // safe default row 0

    // wave-wide max degree (groups diverge only in predicates, not trip count)
    int m = deg;
    m = max(m, __shfl_xor(m, 16, 64));
    m = max(m, __shfl_xor(m, 32, 64));
    m = min(m, 16);

    float4 acc = make_float4(0.f, 0.f, 0.f, 0.f);
    int j = 0;
    for (; j + 4 <= m; j += 4) {
        int r0 = __shfl(eidx, gbase + j + 0, 64);
        int r1 = __shfl(eidx, gbase + j + 1, 64);
        int r2 = __shfl(eidx, gbase + j + 2, 64);
        int r3 = __shfl(eidx, gbase + j + 3, 64);
        float4 v0 = Yn4[(size_t)r0 * 16 + q];    // 4 loads in flight
        float4 v1 = Yn4[(size_t)r1 * 16 + q];
        float4 v2 = Yn4[(size_t)r2 * 16 + q];
        float4 v3 = Yn4[(size_t)r3 * 16 + q];
        if (j + 0 < deg) { acc.x += v0.x; acc.y += v0.y; acc.z += v0.z; acc.w += v0.w; }
        if (j + 1 < deg) { acc.x += v1.x; acc.y += v1.y; acc.z += v1.z; acc.w += v1.w; }
        if (j + 2 < deg) { acc.x += v2.x; acc.y += v2.y; acc.z += v2.z; acc.w += v2.w; }
        if (j + 3 < deg) { acc.x += v3.x; acc.y += v3.y; acc.z += v3.z; acc.w += v3.w; }
    }
    for (; j < m; ++j) {
        int r = __shfl(eidx, gbase + j, 64);
        float4 v = Yn4[(size_t)r * 16 + q];
        if (j < deg) { acc.x += v.x; acc.y += v.y; acc.z += v.z; acc.w += v.w; }
    }
    // rare tail (deg > 16): ~0 nodes for Poisson(4), correctness only
    for (int jj = beg + 16; jj < end; ++jj) {
        int r = elist[jj];
        float4 v = Yn4[(size_t)r * 16 + q];
        acc.x += v.x; acc.y += v.y; acc.z += v.z; acc.w += v.w;
    }

    float4 o;
    o.x = fmaf(dc, acc.x + self.x, bb.x);
    o.y = fmaf(dc, acc.y + self.y, bb.y);
    o.z = fmaf(dc, acc.z + self.z, bb.z);
    o.w = fmaf(dc, acc.w + self.w, bb.w);
    if (relu_out) {
        o.x = fmaxf(o.x, 0.f); o.y = fmaxf(o.y, 0.f);
        o.z = fmaxf(o.z, 0.f); o.w = fmaxf(o.w, 0.f);
    }
    OUT4[(size_t)nid * 16 + q] = o;
}

// ---------------------------------------------------------------------------

extern "C" void kernel_launch(void* const* d_in, const int* in_sizes, int n_in,
                              void* d_out, int out_size, void* d_ws, size_t ws_size,
                              hipStream_t stream) {
    const int*   user_ids = (const int*)d_in[0];
    const int*   item_ids = (const int*)d_in[1];
    const int*   edge     = (const int*)d_in[2];
    const float* ut   = (const float*)d_in[4];
    const float* it   = (const float*)d_in[5];
    const float* W1   = (const float*)d_in[6];
    const float* b1   = (const float*)d_in[7];
    const float* W2   = (const float*)d_in[8];
    const float* b2   = (const float*)d_in[9];
    const float* W3   = (const float*)d_in[10];
    const float* b3   = (const float*)d_in[11];
    const float* linW = (const float*)d_in[12];
    const float* linb = (const float*)d_in[13];

    const int u = in_sizes[0];
    const int iN = in_sizes[1];
    const int e = in_sizes[2] / 2;
    const int n = u + iN;

    // workspace layout
    float* A    = (float*)d_ws;                       // [n,64] node features
    float* dinv = A + (size_t)n * 64;                 // [n]
    int*   cnt  = (int*)(dinv + n);                   // [n]  (reused as cursor)
    int*   offs = cnt + n;                            // [n+1]
    int*   bsum = offs + n + 1;                       // [nb]
    int*   elist = bsum + 1024;                       // [e]
    float* Yn   = (float*)d_out;                      // [n,64] scratch; final out

    const int* erow = edge;
    const int* ecol = edge + e;

    const int B = 256;
    const int nb = (n + 1023) / 1024;

    // ---- CSR build + dinv ----
    hipMemsetAsync(cnt, 0, (size_t)n * sizeof(int), stream);
    k_hist<<<(e + B - 1) / B, B, 0, stream>>>(ecol, cnt, e);
    k_scan1<<<nb, 256, 0, stream>>>(cnt, offs, bsum, n);
    k_scan2<<<1, 512, 0, stream>>>(bsum, nb);
    k_scan3<<<(n + B - 1) / B, B, 0, stream>>>(offs, bsum, n, e);
    k_dinv<<<(n + B - 1) / B, B, 0, stream>>>(cnt, dinv, n);
    hipMemsetAsync(cnt, 0, (size_t)n * sizeof(int), stream);  // cursor
    k_fill<<<(e + B - 1) / B, B, 0, stream>>>(erow, ecol, offs, cnt, elist, e);

    const int gemm_grid = (n + 63) / 64;
    const int gath_grid = (n + 15) / 16;  // 16 nodes/block (16 lanes/node)

    // conv1 (embed fused into GEMM address calc)
    k_gemm<<<gemm_grid, B, 0, stream>>>(nullptr, user_ids, item_ids,
                                        (const float4*)ut, (const float4*)it,
                                        W1, nullptr, Yn, dinv, n, u);
    k_gather<<<gath_grid, B, 0, stream>>>(offs, elist, dinv, (const float4*)Yn,
                                          (const float4*)b1, (float4*)A, n, 1);
    // conv2 (relu applied at gather1 store)
    k_gemm<<<gemm_grid, B, 0, stream>>>(A, nullptr, nullptr, nullptr, nullptr,
                                        W2, nullptr, Yn, dinv, n, u);
    k_gather<<<gath_grid, B, 0, stream>>>(offs, elist, dinv, (const float4*)Yn,
                                          (const float4*)b2, (float4*)A, n, 1);
    // conv3
    k_gemm<<<gemm_grid, B, 0, stream>>>(A, nullptr, nullptr, nullptr, nullptr,
                                        W3, nullptr, Yn, dinv, n, u);
    k_gather<<<gath_grid, B, 0, stream>>>(offs, elist, dinv, (const float4*)Yn,
                                          (const float4*)b3, (float4*)A, n, 0);
    // mean-pool = identity; linear head -> d_out
    k_gemm<<<gemm_grid, B, 0, stream>>>(A, nullptr, nullptr, nullptr, nullptr,
                                        linW, linb, (float*)d_out, nullptr, n, u);
}